// Round 4
// baseline (217.185 us; speedup 1.0000x reference)
//
#include <hip/hip_runtime.h>
#include <math.h>

#define K_TOT 32
#define K_IND 16
#define K_MLP 16
#define DHID  64

// ws layout (ints): P floats [0..16), N floats [16..32), flag @32, dmax_bits @33,
// rp = ((int*)ws)+64, length N+1.
// ws is poisoned 0xAA before every launch: 0xAAAAAAAA is a negative int, which is
// a valid init for atomicMax over float-bits of non-negative floats.

__global__ void prep_kernel(const int* __restrict__ recv,
                            const float* __restrict__ dist, int E, int N,
                            const float* __restrict__ w1,
                            const float* __restrict__ b1,
                            const float* __restrict__ w2,
                            float* __restrict__ wsP,
                            float* __restrict__ wsN,
                            int* __restrict__ wsflag,
                            int* __restrict__ wsdmax,
                            int* __restrict__ rp) {
    int tid = blockIdx.x * blockDim.x + threadIdx.x;
    if (blockIdx.x == 0 && threadIdx.x < 64) {
        int t = threadIdx.x;
        if (t < K_MLP) {
            float P = 0.f, Nn = 0.f;
            for (int j = 0; j < DHID; ++j) {
                float w = w1[j];
                float v = w2[j * K_MLP + t];
                P  += fmaxf(w, 0.f) * v;
                Nn += fminf(w, 0.f) * v;
            }
            wsP[t] = P; wsN[t] = Nn;
        }
        bool nz = (b1[t] != 0.f);
        unsigned long long mask = __ballot(nz);
        if (t == 0) *wsflag = (mask == 0ull) ? 1 : 0;
    }
    // global max|d| for the bound-M softmax
    float dm = 0.f;
    int stride = gridDim.x * blockDim.x;
    for (int e = tid; e < E; e += stride) dm = fmaxf(dm, fabsf(dist[e]));
#pragma unroll
    for (int off = 32; off; off >>= 1) dm = fmaxf(dm, __shfl_xor(dm, off));
    if ((threadIdx.x & 63) == 0) atomicMax(wsdmax, __float_as_int(dm));
    // row_ptr via lower_bound on sorted receivers
    if (tid <= N) {
        int lo = 0, hi = E;
        while (lo < hi) {
            int mid = (lo + hi) >> 1;
            if (recv[mid] < tid) lo = mid + 1; else hi = mid;
        }
        rp[tid] = lo;
    }
}

// One wave per node. es = lane>>3 (8 edge slots), cg = lane&7 (channel group).
// Each lane owns 4 channels: indicator {2cg, 2cg+1}, mlp {2cg+16, 2cg+17}.
// Fast path (b1==0, b==2): pd = t*t, softmax with precomputed bound M_k = qa_k*dmax
// -> pure sums, no online rescale, no powf. Slow path: generic fallback.
__global__ __launch_bounds__(256) void graph_kernel(
        const float* __restrict__ nodes,
        const float* __restrict__ dist,
        const float* __restrict__ padv,
        const int*   __restrict__ send,
        const float* __restrict__ w1,
        const float* __restrict__ b1,
        const float* __restrict__ w2,
        const float* __restrict__ b2,
        const float* __restrict__ a_p,
        const float* __restrict__ b_p,
        const float* __restrict__ wg_self,
        const float* __restrict__ wg_gath,
        const float* __restrict__ bg,
        const float* __restrict__ wsP,
        const float* __restrict__ wsN,
        const int*   __restrict__ wsflag,
        const int*   __restrict__ wsdmax,
        const int*   __restrict__ rp,
        float* __restrict__ out,
        int N) {
    int wave = blockIdx.x * (blockDim.x >> 6) + (threadIdx.x >> 6);
    if (wave >= N) return;
    int n    = wave;
    int lane = threadIdx.x & 63;
    int es   = lane >> 3;       // edge slot 0..7
    int cg   = lane & 7;        // channel group 0..7
    int c0   = cg << 1;         // first owned indicator channel

    float a_c = fminf(fmaxf(a_p[0], 0.f), 1.f);
    float am  = 1.f - a_c;
    float bc  = fabsf(b_p[0]);
    bool  bsq = (bc == 2.0f);
    bool  fastf = (*wsflag != 0) && bsq;

    float P0 = wsP[c0], P1 = wsP[c0 + 1];
    float N0 = wsN[c0], N1 = wsN[c0 + 1];

    const float* nrow = nodes + n * K_TOT;
    float2 nrI = *(const float2*)(nrow + c0);
    float2 nrM = *(const float2*)(nrow + c0 + 16);
    float aI0 = a_c * nrI.x, aI1 = a_c * nrI.y;
    float aM0 = a_c * nrM.x, aM1 = a_c * nrM.y;

    float lo0 = (float)c0 * 0.0625f;
    float hi0 = lo0 + 0.0625f;
    float lo1 = hi0;
    float hi1 = lo1 + 0.0625f;

    int e0 = rp[n], eEnd = rp[n + 1];
    int len = eEnd - e0;

    float cI0 = 0.f, sI0 = 0.f, cI1 = 0.f, sI1 = 0.f;   // indicator accums
    float gI0, gI1, gM0, gM1;

    if (__builtin_amdgcn_readfirstlane((int)fastf)) {
        // ---------------- FAST PATH ----------------
        float dmax = __int_as_float(*wsdmax);
        float negM0 = -fmaxf(fabsf(P0), fabsf(N0)) * dmax;
        float negM1 = -fmaxf(fabsf(P1), fabsf(N1)) * dmax;

        float l0 = 0.f, ac0 = 0.f, l1 = 0.f, ac1 = 0.f;

        if (len > 0) {
            int last = len - 1;
            // pipeline stage A
            int iA = es;
            int eA = e0 + (iA < last ? iA : last);
            bool vA = iA < len;
            float dA = dist[eA]; int sA = send[eA]; float pA = padv[eA];
            float2 nsIA = *(const float2*)(nodes + sA * K_TOT + c0);
            float2 nsMA = *(const float2*)(nodes + sA * K_TOT + c0 + 16);

            for (int base = 0; base < len; base += 8) {
                // prefetch stage B
                int iB = base + 8 + es;
                int eB = e0 + (iB < last ? iB : last);
                float dB = dist[eB]; int sB = send[eB]; float pB = padv[eB];
                float2 nsIB = *(const float2*)(nodes + sB * K_TOT + c0);
                float2 nsMB = *(const float2*)(nodes + sB * K_TOT + c0 + 16);

                // compute on stage A
                float d  = dA;
                float pe = vA ? pA : 0.f;
                float tI0 = fmaf(-am, nsIA.x, aI0);
                float tI1 = fmaf(-am, nsIA.y, aI1);
                float tM0 = fmaf(-am, nsMA.x, aM0);
                float tM1 = fmaf(-am, nsMA.y, aM1);
                float pdI0 = tI0 * tI0, pdI1 = tI1 * tI1;
                float pdM0 = tM0 * tM0, pdM1 = tM1 * tM1;

                bool in0 = vA && (d > lo0) && (d < hi0);
                bool in1 = vA && (d > lo1) && (d < hi1);
                cI0 += in0 ? 1.f : 0.f;
                sI0 += in0 ? pe * pdI0 : 0.f;
                cI1 += in1 ? 1.f : 0.f;
                sI1 += in1 ? pe * pdI1 : 0.f;

                float q0 = (d > 0.f) ? P0 : N0;
                float q1 = (d > 0.f) ? P1 : N1;
                float p0 = __expf(fmaf(d, q0, negM0));
                float p1 = __expf(fmaf(d, q1, negM1));
                p0 = vA ? p0 : 0.f;
                p1 = vA ? p1 : 0.f;
                l0 += p0;  ac0 = fmaf(p0, pe * pdM0, ac0);
                l1 += p1;  ac1 = fmaf(p1, pe * pdM1, ac1);

                // rotate
                vA = iB < len;
                dA = dB; pA = pB; nsIA = nsIB; nsMA = nsMB;
            }
        }

        // merge across the 8 edge slots (lane-id bits 3,4,5)
#pragma unroll
        for (int off = 8; off <= 32; off <<= 1) {
            cI0 += __shfl_xor(cI0, off);  sI0 += __shfl_xor(sI0, off);
            cI1 += __shfl_xor(cI1, off);  sI1 += __shfl_xor(sI1, off);
            l0  += __shfl_xor(l0,  off);  ac0 += __shfl_xor(ac0, off);
            l1  += __shfl_xor(l1,  off);  ac1 += __shfl_xor(ac1, off);
        }
        gI0 = sI0 / (cI0 + 1e-5f);
        gI1 = sI1 / (cI1 + 1e-5f);
        gM0 = (l0 > 0.f) ? (ac0 / l0) : 0.f;
        gM1 = (l1 > 0.f) ? (ac1 / l1) : 0.f;
    } else {
        // ---------------- SLOW GENERIC PATH ----------------
        float m0 = -INFINITY, l0 = 0.f, ac0 = 0.f;
        float m1 = -INFINITY, l1 = 0.f, ac1 = 0.f;

        for (int i = es; i < len; i += 8) {
            int e = e0 + i;
            float d  = dist[e];
            int   s  = send[e];
            float pe = padv[e];
            float2 nsI = *(const float2*)(nodes + s * K_TOT + c0);
            float2 nsM = *(const float2*)(nodes + s * K_TOT + c0 + 16);
            float tI0 = fabsf(fmaf(-am, nsI.x, aI0));
            float tI1 = fabsf(fmaf(-am, nsI.y, aI1));
            float tM0 = fabsf(fmaf(-am, nsM.x, aM0));
            float tM1 = fabsf(fmaf(-am, nsM.y, aM1));
            float pdI0 = powf(tI0, bc), pdI1 = powf(tI1, bc);
            float pdM0 = powf(tM0, bc), pdM1 = powf(tM1, bc);

            bool in0 = (d > lo0) && (d < hi0);
            bool in1 = (d > lo1) && (d < hi1);
            cI0 += in0 ? 1.f : 0.f;  sI0 += in0 ? pe * pdI0 : 0.f;
            cI1 += in1 ? 1.f : 0.f;  sI1 += in1 ? pe * pdI1 : 0.f;

            float mlp0 = 0.f, mlp1 = 0.f;   // b2 cancels in the softmax ratio
            for (int j = 0; j < DHID; ++j) {
                float h = fmaxf(fmaf(d, w1[j], b1[j]), 0.f);
                mlp0 = fmaf(h, w2[j * K_MLP + c0], mlp0);
                mlp1 = fmaf(h, w2[j * K_MLP + c0 + 1], mlp1);
            }
            {
                float mn = fmaxf(m0, mlp0);
                float al = (m0 == -INFINITY) ? 0.f : __expf(m0 - mn);
                float p  = __expf(mlp0 - mn);
                l0  = fmaf(l0, al, p);
                ac0 = fmaf(ac0, al, p * pe * pdM0);
                m0 = mn;
            }
            {
                float mn = fmaxf(m1, mlp1);
                float al = (m1 == -INFINITY) ? 0.f : __expf(m1 - mn);
                float p  = __expf(mlp1 - mn);
                l1  = fmaf(l1, al, p);
                ac1 = fmaf(ac1, al, p * pe * pdM1);
                m1 = mn;
            }
        }

#pragma unroll
        for (int off = 8; off <= 32; off <<= 1) {
            cI0 += __shfl_xor(cI0, off);  sI0 += __shfl_xor(sI0, off);
            cI1 += __shfl_xor(cI1, off);  sI1 += __shfl_xor(sI1, off);
            {
                float m2 = __shfl_xor(m0, off), l2 = __shfl_xor(l0, off), a2 = __shfl_xor(ac0, off);
                float mn = fmaxf(m0, m2);
                float f1 = (m0 == -INFINITY) ? 0.f : __expf(m0 - mn);
                float f2 = (m2 == -INFINITY) ? 0.f : __expf(m2 - mn);
                l0  = l0 * f1 + l2 * f2;
                ac0 = ac0 * f1 + a2 * f2;
                m0 = mn;
            }
            {
                float m2 = __shfl_xor(m1, off), l2 = __shfl_xor(l1, off), a2 = __shfl_xor(ac1, off);
                float mn = fmaxf(m1, m2);
                float f1 = (m1 == -INFINITY) ? 0.f : __expf(m1 - mn);
                float f2 = (m2 == -INFINITY) ? 0.f : __expf(m2 - mn);
                l1  = l1 * f1 + l2 * f2;
                ac1 = ac1 * f1 + a2 * f2;
                m1 = mn;
            }
        }
        gI0 = sI0 / (cI0 + 1e-5f);
        gI1 = sI1 / (cI1 + 1e-5f);
        gM0 = (l0 > 0.f) ? (ac0 / l0) : 0.f;
        gM1 = (l1 > 0.f) ? (ac1 / l1) : 0.f;
    }

    // ---- redistribute: lane (h*32+oc) needs g of channel oc = lane&31 ----
    int c = lane & 31;
    int srcI = c >> 1;            // lane (es=0,cg=c>>1) holds ind channel c
    int srcM = (c & 15) >> 1;     // lane holding mlp channel c (c>=16)
    float gi0 = __shfl(gI0, srcI), gi1 = __shfl(gI1, srcI);
    float gm0 = __shfl(gM0, srcM), gm1 = __shfl(gM1, srcM);
    float pre_g = (c < 16) ? ((c & 1) ? gi1 : gi0)
                           : ((c & 1) ? gm1 : gm0);
    float pre_n = nrow[c];        // L1 hit (row already touched)

    // ---- fused epilogue: out[n][oc] = relu(sum_j nr_j*Ws[j][oc] + g_j*Wg[j][oc] + bg[oc])
    int h  = lane >> 5;
    int oc = lane & 31;
    float o = 0.f;
    int jbase = h * 16;
#pragma unroll
    for (int jj = 0; jj < 16; ++jj) {
        int j = jbase + jj;
        float gj = __shfl(pre_g, j);
        float nj = __shfl(pre_n, j);
        o = fmaf(nj, wg_self[j * K_TOT + oc], o);
        o = fmaf(gj, wg_gath[j * K_TOT + oc], o);
    }
    o += __shfl_xor(o, 32);
    if (h == 0) {
        out[n * K_TOT + oc] = fmaxf(o + bg[oc], 0.f);
    }
}

extern "C" void kernel_launch(void* const* d_in, const int* in_sizes, int n_in,
                              void* d_out, int out_size, void* d_ws, size_t ws_size,
                              hipStream_t stream) {
    const float* nodes   = (const float*)d_in[0];
    const float* dist    = (const float*)d_in[1];
    const float* padv    = (const float*)d_in[2];
    const int*   recv    = (const int*)d_in[3];
    const int*   send    = (const int*)d_in[4];
    const float* w1      = (const float*)d_in[5];
    const float* b1      = (const float*)d_in[6];
    const float* w2      = (const float*)d_in[7];
    const float* b2      = (const float*)d_in[8];
    const float* a_p     = (const float*)d_in[9];
    const float* b_p     = (const float*)d_in[10];
    const float* wg_self = (const float*)d_in[11];
    const float* wg_gath = (const float*)d_in[12];
    const float* bg      = (const float*)d_in[13];
    float* out = (float*)d_out;

    int N = in_sizes[0] / K_TOT;
    int E = in_sizes[1];

    float* wsf    = (float*)d_ws;
    float* wsP    = wsf;
    float* wsN    = wsf + 16;
    int*   wsflag = (int*)d_ws + 32;
    int*   wsdmax = (int*)d_ws + 33;
    int*   rp     = (int*)d_ws + 64;

    prep_kernel<<<(N + 1 + 255) / 256, 256, 0, stream>>>(recv, dist, E, N,
                                                         w1, b1, w2,
                                                         wsP, wsN, wsflag, wsdmax, rp);
    graph_kernel<<<(N + 3) / 4, 256, 0, stream>>>(
        nodes, dist, padv, send, w1, b1, w2, b2, a_p, b_p,
        wg_self, wg_gath, bg, wsP, wsN, wsflag, wsdmax, rp, out, N);
}

// Round 5
// 178.995 us; speedup vs baseline: 1.2134x; 1.2134x over previous
//
#include <hip/hip_runtime.h>
#include <math.h>

#define K_TOT 32
#define K_IND 16
#define K_MLP 16
#define DHID  64

// ws layout (ints): P floats [0..16), N floats [16..32), flag @32,
// rp = ((int*)ws)+64, length N+1.

// Prep: block 0 wave 0 computes collapsed-MLP constants
//   P_k = sum_{j: w1_j>0} w1_j*w2[j][k], N_k = sum_{j: w1_j<0} w1_j*w2[j][k]
// and flag = (all b1 == 0). All threads t<=N: rp[t] = lower_bound(recv, t).
__global__ void prep_kernel(const int* __restrict__ recv, int E, int N,
                            const float* __restrict__ w1,
                            const float* __restrict__ b1,
                            const float* __restrict__ w2,
                            float* __restrict__ wsP,
                            float* __restrict__ wsN,
                            int* __restrict__ wsflag,
                            int* __restrict__ rp) {
    if (blockIdx.x == 0 && threadIdx.x < 64) {
        int t = threadIdx.x;
        if (t < K_MLP) {
            float P = 0.f, Nn = 0.f;
            for (int j = 0; j < DHID; ++j) {
                float w = w1[j];
                float v = w2[j * K_MLP + t];
                P  += fmaxf(w, 0.f) * v;
                Nn += fminf(w, 0.f) * v;
            }
            wsP[t] = P; wsN[t] = Nn;
        }
        bool nz = (b1[t] != 0.f);
        unsigned long long mask = __ballot(nz);
        if (t == 0) *wsflag = (mask == 0ull) ? 1 : 0;
    }
    int tid = blockIdx.x * blockDim.x + threadIdx.x;
    if (tid <= N) {
        int lo = 0, hi = E;
        while (lo < hi) {
            int mid = (lo + hi) >> 1;
            if (recv[mid] < tid) lo = mid + 1; else hi = mid;
        }
        rp[tid] = lo;
    }
}

// One wave per node. eg = lane>>4 (4 edge slots), cc = lane&15 (channel pair:
// indicator channel cc + mlp channel cc+16). Edge scalars loaded 64-at-a-time
// coalesced (clamped idx -> no guards), broadcast per 4-edge group via
// ds_bpermute. Wave-uniform fast/slow split: fast path (all b1==0 && b==2)
// has NO powf and a bound-M softmax (M = max|q|*max|d| over the segment)
// -> pure sums, no online rescale.
__global__ __launch_bounds__(256) void graph_kernel(
        const float* __restrict__ nodes,
        const float* __restrict__ dist,
        const float* __restrict__ padv,
        const int*   __restrict__ send,
        const float* __restrict__ w1,
        const float* __restrict__ b1,
        const float* __restrict__ w2,
        const float* __restrict__ b2,
        const float* __restrict__ a_p,
        const float* __restrict__ b_p,
        const float* __restrict__ wg_self,
        const float* __restrict__ wg_gath,
        const float* __restrict__ bg,
        const float* __restrict__ wsP,
        const float* __restrict__ wsN,
        const int*   __restrict__ wsflag,
        const int*   __restrict__ rp,
        float* __restrict__ out,
        int N) {
    int wave = blockIdx.x * (blockDim.x >> 6) + (threadIdx.x >> 6);
    if (wave >= N) return;
    int n    = wave;
    int lane = threadIdx.x & 63;
    int eg   = lane >> 4;   // edge slot 0..3
    int cc   = lane & 15;   // channel pair index

    float a_c = fminf(fmaxf(a_p[0], 0.f), 1.f);
    float am  = 1.f - a_c;
    float bc  = fabsf(b_p[0]);
    bool  fastf = (*wsflag != 0) && (bc == 2.0f);

    float Pk = wsP[cc];
    float Nk = wsN[cc];

    const float* nrow = nodes + n * K_TOT;
    float nr0 = nrow[cc];
    float nr1 = nrow[cc + 16];
    float anr0 = a_c * nr0;
    float anr1 = a_c * nr1;

    int e0 = rp[n], eEnd = rp[n + 1];
    int len = eEnd - e0;

    float lo = (float)cc * 0.0625f;
    float hi = lo + 0.0625f;

    float cnt = 0.f, si = 0.f;        // indicator (channel cc)
    float l = 0.f, acc = 0.f;         // softmax  (channel cc+16)
    float g_ind, g_mlp;

    int egb = eg << 2;                // bpermute byte base for group 0

    if (__builtin_amdgcn_readfirstlane((int)fastf)) {
        // ---------------- FAST PATH (no powf, bound-M softmax) ----------------
        // pre-pass: max|d| over the segment (usually 1 batch, stays in L1)
        float dm = 0.f;
        for (int base = 0; base < len; base += 64) {
            int idx = base + lane;
            int cmax = len - 1;
            idx = idx < cmax ? idx : cmax;
            dm = fmaxf(dm, fabsf(dist[e0 + idx]));
        }
#pragma unroll
        for (int off = 32; off; off >>= 1) dm = fmaxf(dm, __shfl_xor(dm, off));
        float negM = -fmaxf(fabsf(Pk), fabsf(Nk)) * dm;

        for (int base = 0; base < len; base += 64) {
            int rem = len - base;
            int ci = base + lane;
            int cmax = len - 1;
            ci = ci < cmax ? ci : cmax;     // clamp -> no overfetch, no guards
            int e = e0 + ci;
            float dl = dist[e];
            int   sl = send[e];
            float pl = padv[e];
            int nG = (rem + 3) >> 2;
            nG = nG < 16 ? nG : 16;
            int byteIdx = egb;
            for (int g2 = 0; g2 < nG; ++g2, byteIdx += 16) {
                float d  = __int_as_float(__builtin_amdgcn_ds_bpermute(byteIdx, __float_as_int(dl)));
                int   s  = __builtin_amdgcn_ds_bpermute(byteIdx, sl);
                float pe = __int_as_float(__builtin_amdgcn_ds_bpermute(byteIdx, __float_as_int(pl)));
                bool valid = (base + (g2 << 2) + eg) < len;

                const float* nsrow = nodes + (s * K_TOT + cc);
                float ns0 = nsrow[0];
                float ns1 = nsrow[16];   // same base reg, +64B imm offset

                float t0 = fmaf(-am, ns0, anr0);
                float t1 = fmaf(-am, ns1, anr1);
                float pd0 = t0 * t0;
                float pd1 = t1 * t1;

                bool inb = valid && (d > lo) && (d < hi);
                cnt += inb ? 1.f : 0.f;
                si  += inb ? pe * pd0 : 0.f;

                float q = (d > 0.f) ? Pk : Nk;
                float p = __expf(fmaf(d, q, negM));
                p = valid ? p : 0.f;
                l += p;
                acc = fmaf(p, pe * pd1, acc);
            }
        }

        // merge the 4 edge-slot partials (eg = lane bits 4,5)
#pragma unroll
        for (int off = 16; off <= 32; off <<= 1) {
            cnt += __shfl_xor(cnt, off);
            si  += __shfl_xor(si,  off);
            l   += __shfl_xor(l,   off);
            acc += __shfl_xor(acc, off);
        }
        g_ind = si / (cnt + 1e-5f);
        g_mlp = (l > 0.f) ? (acc / l) : 0.f;
    } else {
        // ---------------- SLOW GENERIC PATH ----------------
        float m_on = -INFINITY;
        for (int i = eg; i < len; i += 4) {
            int e = e0 + i;
            float d  = dist[e];
            int   s  = send[e];
            float pe = padv[e];
            const float* nsrow = nodes + (s * K_TOT + cc);
            float ns0 = nsrow[0];
            float ns1 = nsrow[16];
            float t0 = fabsf(fmaf(-am, ns0, anr0));
            float t1 = fabsf(fmaf(-am, ns1, anr1));
            float pd0 = powf(t0, bc);
            float pd1 = powf(t1, bc);

            bool inb = (d > lo) && (d < hi);
            cnt += inb ? 1.f : 0.f;
            si  += inb ? pe * pd0 : 0.f;

            float mlp = 0.f;   // b2 cancels in the softmax ratio
            for (int j = 0; j < DHID; ++j) {
                float h = fmaxf(fmaf(d, w1[j], b1[j]), 0.f);
                mlp = fmaf(h, w2[j * K_MLP + cc], mlp);
            }
            float mn = fmaxf(m_on, mlp);
            float al = (m_on == -INFINITY) ? 0.f : __expf(m_on - mn);
            float p  = __expf(mlp - mn);
            l   = fmaf(l, al, p);
            acc = fmaf(acc, al, p * pe * pd1);
            m_on = mn;
        }
#pragma unroll
        for (int off = 16; off <= 32; off <<= 1) {
            cnt += __shfl_xor(cnt, off);
            si  += __shfl_xor(si,  off);
            float m2 = __shfl_xor(m_on, off), l2 = __shfl_xor(l, off), a2 = __shfl_xor(acc, off);
            float mn = fmaxf(m_on, m2);
            float f1 = (m_on == -INFINITY) ? 0.f : __expf(m_on - mn);
            float f2 = (m2   == -INFINITY) ? 0.f : __expf(m2 - mn);
            l   = l * f1 + l2 * f2;
            acc = acc * f1 + a2 * f2;
            m_on = mn;
        }
        g_ind = si / (cnt + 1e-5f);
        g_mlp = (l > 0.f) ? (acc / l) : 0.f;
    }

    // fused epilogue: out[n][oc] = relu(sum_j nr_j*Ws[j][oc] + g_j*Wg[j][oc] + bg[oc])
    // h = lane>>5 covers j in [h*16, h*16+16); oc = lane&31.
    // lane j (j<32) holds (g,nr) of exactly channel j via the pre_* selects
    // (after the merge, g_* are uniform across the 4 edge slots).
    int h  = lane >> 5;
    int oc = lane & 31;
    float pre_g = ((lane >> 4) & 1) ? g_mlp : g_ind;
    float pre_n = ((lane >> 4) & 1) ? nr1 : nr0;

    float o = 0.f;
    int jbase = h * 16;
#pragma unroll
    for (int jj = 0; jj < 16; ++jj) {
        int j = jbase + jj;
        float gj = __shfl(pre_g, j);
        float nj = __shfl(pre_n, j);
        o = fmaf(nj, wg_self[j * K_TOT + oc], o);
        o = fmaf(gj, wg_gath[j * K_TOT + oc], o);
    }
    o += __shfl_xor(o, 32);
    if (h == 0) {
        out[n * K_TOT + oc] = fmaxf(o + bg[oc], 0.f);
    }
}

extern "C" void kernel_launch(void* const* d_in, const int* in_sizes, int n_in,
                              void* d_out, int out_size, void* d_ws, size_t ws_size,
                              hipStream_t stream) {
    const float* nodes   = (const float*)d_in[0];
    const float* dist    = (const float*)d_in[1];
    const float* padv    = (const float*)d_in[2];
    const int*   recv    = (const int*)d_in[3];
    const int*   send    = (const int*)d_in[4];
    const float* w1      = (const float*)d_in[5];
    const float* b1      = (const float*)d_in[6];
    const float* w2      = (const float*)d_in[7];
    const float* b2      = (const float*)d_in[8];
    const float* a_p     = (const float*)d_in[9];
    const float* b_p     = (const float*)d_in[10];
    const float* wg_self = (const float*)d_in[11];
    const float* wg_gath = (const float*)d_in[12];
    const float* bg      = (const float*)d_in[13];
    float* out = (float*)d_out;

    int N = in_sizes[0] / K_TOT;
    int E = in_sizes[1];

    float* wsf    = (float*)d_ws;
    float* wsP    = wsf;
    float* wsN    = wsf + 16;
    int*   wsflag = (int*)d_ws + 32;
    int*   rp     = (int*)d_ws + 64;

    prep_kernel<<<(N + 1 + 255) / 256, 256, 0, stream>>>(recv, E, N, w1, b1, w2,
                                                         wsP, wsN, wsflag, rp);
    graph_kernel<<<(N + 3) / 4, 256, 0, stream>>>(
        nodes, dist, padv, send, w1, b1, w2, b2, a_p, b_p,
        wg_self, wg_gath, bg, wsP, wsN, wsflag, rp, out, N);
}

// Round 6
// 172.234 us; speedup vs baseline: 1.2610x; 1.0393x over previous
//
#include <hip/hip_runtime.h>
#include <math.h>

#define K_TOT 32
#define K_IND 16
#define K_MLP 16
#define DHID  64

// ws layout (ints): P floats [0..16), N floats [16..32), flag @32,
// rp = ((int*)ws)+64, length N+1.

// Prep: block 0 wave 0 computes collapsed-MLP constants
//   P_k = sum_{j: w1_j>0} w1_j*w2[j][k], N_k = sum_{j: w1_j<0} w1_j*w2[j][k]
// and flag = (all b1 == 0). All threads t<=N: rp[t] = lower_bound(recv, t).
__global__ void prep_kernel(const int* __restrict__ recv, int E, int N,
                            const float* __restrict__ w1,
                            const float* __restrict__ b1,
                            const float* __restrict__ w2,
                            float* __restrict__ wsP,
                            float* __restrict__ wsN,
                            int* __restrict__ wsflag,
                            int* __restrict__ rp) {
    if (blockIdx.x == 0 && threadIdx.x < 64) {
        int t = threadIdx.x;
        if (t < K_MLP) {
            float P = 0.f, Nn = 0.f;
            for (int j = 0; j < DHID; ++j) {
                float w = w1[j];
                float v = w2[j * K_MLP + t];
                P  += fmaxf(w, 0.f) * v;
                Nn += fminf(w, 0.f) * v;
            }
            wsP[t] = P; wsN[t] = Nn;
        }
        bool nz = (b1[t] != 0.f);
        unsigned long long mask = __ballot(nz);
        if (t == 0) *wsflag = (mask == 0ull) ? 1 : 0;
    }
    int tid = blockIdx.x * blockDim.x + threadIdx.x;
    if (tid <= N) {
        int lo = 0, hi = E;
        while (lo < hi) {
            int mid = (lo + hi) >> 1;
            if (recv[mid] < tid) lo = mid + 1; else hi = mid;
        }
        rp[tid] = lo;
    }
}

// One wave per node. eg = lane>>4 (4 edge slots), cc = lane&15 (channel pair:
// indicator channel cc + mlp channel cc+16).
// Fast path (all b1==0 && b==2 && len<=64): no powf; bound-M softmax with
// max|d| computed by a register reduce on ONE coalesced dist load; per-group
// edge scalars loaded directly (16-lane broadcast via L1) -> all groups'
// load chains independent; 2x group unroll for MLP overlap.
__global__ __launch_bounds__(256) void graph_kernel(
        const float* __restrict__ nodes,
        const float* __restrict__ dist,
        const float* __restrict__ padv,
        const int*   __restrict__ send,
        const float* __restrict__ w1,
        const float* __restrict__ b1,
        const float* __restrict__ w2,
        const float* __restrict__ b2,
        const float* __restrict__ a_p,
        const float* __restrict__ b_p,
        const float* __restrict__ wg_self,
        const float* __restrict__ wg_gath,
        const float* __restrict__ bg,
        const float* __restrict__ wsP,
        const float* __restrict__ wsN,
        const int*   __restrict__ wsflag,
        const int*   __restrict__ rp,
        float* __restrict__ out,
        int N) {
    int wave = blockIdx.x * (blockDim.x >> 6) + (threadIdx.x >> 6);
    if (wave >= N) return;
    int n    = wave;
    int lane = threadIdx.x & 63;
    int eg   = lane >> 4;   // edge slot 0..3
    int cc   = lane & 15;   // channel pair index

    float a_c = fminf(fmaxf(a_p[0], 0.f), 1.f);
    float am  = 1.f - a_c;
    float bc  = fabsf(b_p[0]);

    float Pk = wsP[cc];
    float Nk = wsN[cc];

    const float* nrow = nodes + n * K_TOT;
    float nr0 = nrow[cc];
    float nr1 = nrow[cc + 16];
    float anr0 = a_c * nr0;
    float anr1 = a_c * nr1;

    int e0 = rp[n], eEnd = rp[n + 1];
    int len = eEnd - e0;

    float lo = (float)cc * 0.0625f;
    float hi = lo + 0.0625f;

    float cnt = 0.f, si = 0.f;        // indicator (channel cc)
    float l = 0.f, acc = 0.f;         // softmax  (channel cc+16)
    float g_ind, g_mlp;

    bool fastf = (*wsflag != 0) && (bc == 2.0f) && (len <= 64);

    if (__builtin_amdgcn_readfirstlane((int)fastf)) {
        // ---------------- FAST PATH ----------------
        if (len > 0) {
            // max|d| from ONE coalesced load + register butterfly
            int idx = lane < len ? lane : len - 1;
            float dm = fabsf(dist[e0 + idx]);
#pragma unroll
            for (int off = 32; off; off >>= 1) dm = fmaxf(dm, __shfl_xor(dm, off));
            float negM = -fmaxf(fabsf(Pk), fabsf(Nk)) * dm;

            int nG = (len + 3) >> 2;
            int last = len - 1;

#define GRP_BODY(G)                                                          \
            {                                                                \
                int i = ((G) << 2) + eg;                                     \
                bool valid = i < len;                                        \
                int ii = valid ? i : last;                                   \
                float d  = dist[e0 + ii];                                    \
                int   s  = send[e0 + ii];                                    \
                float pe = padv[e0 + ii];                                    \
                const float* nsrow = nodes + (s * K_TOT + cc);               \
                float ns0 = nsrow[0];                                        \
                float ns1 = nsrow[16];                                       \
                float t0 = fmaf(-am, ns0, anr0);                             \
                float t1 = fmaf(-am, ns1, anr1);                             \
                float pd0 = t0 * t0;                                         \
                float pd1 = t1 * t1;                                         \
                bool inb = valid && (d > lo) && (d < hi);                    \
                cnt += inb ? 1.f : 0.f;                                      \
                si   = inb ? fmaf(pe, pd0, si) : si;                         \
                float q = (d > 0.f) ? Pk : Nk;                               \
                float p = __expf(fmaf(d, q, negM));                          \
                p = valid ? p : 0.f;                                         \
                l += p;                                                      \
                acc = fmaf(p, pe * pd1, acc);                                \
            }

            int g = 0;
            for (; g + 2 <= nG; g += 2) {
                GRP_BODY(g)
                GRP_BODY(g + 1)
            }
            if (g < nG) {
                GRP_BODY(g)
            }
#undef GRP_BODY
        }

        // merge the 4 edge-slot partials (eg = lane bits 4,5)
#pragma unroll
        for (int off = 16; off <= 32; off <<= 1) {
            cnt += __shfl_xor(cnt, off);
            si  += __shfl_xor(si,  off);
            l   += __shfl_xor(l,   off);
            acc += __shfl_xor(acc, off);
        }
        g_ind = si / (cnt + 1e-5f);
        g_mlp = (l > 0.f) ? (acc / l) : 0.f;
    } else {
        // ---------------- SLOW GENERIC PATH ----------------
        float m_on = -INFINITY;
        for (int i = eg; i < len; i += 4) {
            int e = e0 + i;
            float d  = dist[e];
            int   s  = send[e];
            float pe = padv[e];
            const float* nsrow = nodes + (s * K_TOT + cc);
            float ns0 = nsrow[0];
            float ns1 = nsrow[16];
            float t0 = fabsf(fmaf(-am, ns0, anr0));
            float t1 = fabsf(fmaf(-am, ns1, anr1));
            float pd0 = powf(t0, bc);
            float pd1 = powf(t1, bc);

            bool inb = (d > lo) && (d < hi);
            cnt += inb ? 1.f : 0.f;
            si  += inb ? pe * pd0 : 0.f;

            float mlp = 0.f;   // b2 cancels in the softmax ratio
            for (int j = 0; j < DHID; ++j) {
                float h = fmaxf(fmaf(d, w1[j], b1[j]), 0.f);
                mlp = fmaf(h, w2[j * K_MLP + cc], mlp);
            }
            float mn = fmaxf(m_on, mlp);
            float al = (m_on == -INFINITY) ? 0.f : __expf(m_on - mn);
            float p  = __expf(mlp - mn);
            l   = fmaf(l, al, p);
            acc = fmaf(acc, al, p * pe * pd1);
            m_on = mn;
        }
#pragma unroll
        for (int off = 16; off <= 32; off <<= 1) {
            cnt += __shfl_xor(cnt, off);
            si  += __shfl_xor(si,  off);
            float m2 = __shfl_xor(m_on, off), l2 = __shfl_xor(l, off), a2 = __shfl_xor(acc, off);
            float mn = fmaxf(m_on, m2);
            float f1 = (m_on == -INFINITY) ? 0.f : __expf(m_on - mn);
            float f2 = (m2   == -INFINITY) ? 0.f : __expf(m2 - mn);
            l   = l * f1 + l2 * f2;
            acc = acc * f1 + a2 * f2;
            m_on = mn;
        }
        g_ind = si / (cnt + 1e-5f);
        g_mlp = (l > 0.f) ? (acc / l) : 0.f;
    }

    // fused epilogue: out[n][oc] = relu(sum_j nr_j*Ws[j][oc] + g_j*Wg[j][oc] + bg[oc])
    // h = lane>>5 covers j in [h*16, h*16+16); oc = lane&31.
    // lane j (j<32) holds (g,nr) of exactly channel j via the pre_* selects
    // (after the merge, g_* are uniform across the 4 edge slots).
    int h  = lane >> 5;
    int oc = lane & 31;
    float pre_g = ((lane >> 4) & 1) ? g_mlp : g_ind;
    float pre_n = ((lane >> 4) & 1) ? nr1 : nr0;

    float o_s = 0.f, o_g = 0.f;
    int jbase = h * 16;
#pragma unroll
    for (int jj = 0; jj < 16; ++jj) {
        int j = jbase + jj;
        float gj = __shfl(pre_g, j);
        float nj = __shfl(pre_n, j);
        o_s = fmaf(nj, wg_self[j * K_TOT + oc], o_s);
        o_g = fmaf(gj, wg_gath[j * K_TOT + oc], o_g);
    }
    float o = o_s + o_g;
    o += __shfl_xor(o, 32);
    if (h == 0) {
        out[n * K_TOT + oc] = fmaxf(o + bg[oc], 0.f);
    }
}

extern "C" void kernel_launch(void* const* d_in, const int* in_sizes, int n_in,
                              void* d_out, int out_size, void* d_ws, size_t ws_size,
                              hipStream_t stream) {
    const float* nodes   = (const float*)d_in[0];
    const float* dist    = (const float*)d_in[1];
    const float* padv    = (const float*)d_in[2];
    const int*   recv    = (const int*)d_in[3];
    const int*   send    = (const int*)d_in[4];
    const float* w1      = (const float*)d_in[5];
    const float* b1      = (const float*)d_in[6];
    const float* w2      = (const float*)d_in[7];
    const float* b2      = (const float*)d_in[8];
    const float* a_p     = (const float*)d_in[9];
    const float* b_p     = (const float*)d_in[10];
    const float* wg_self = (const float*)d_in[11];
    const float* wg_gath = (const float*)d_in[12];
    const float* bg      = (const float*)d_in[13];
    float* out = (float*)d_out;

    int N = in_sizes[0] / K_TOT;
    int E = in_sizes[1];

    float* wsf    = (float*)d_ws;
    float* wsP    = wsf;
    float* wsN    = wsf + 16;
    int*   wsflag = (int*)d_ws + 32;
    int*   rp     = (int*)d_ws + 64;

    prep_kernel<<<(N + 1 + 255) / 256, 256, 0, stream>>>(recv, E, N, w1, b1, w2,
                                                         wsP, wsN, wsflag, rp);
    graph_kernel<<<(N + 3) / 4, 256, 0, stream>>>(
        nodes, dist, padv, send, w1, b1, w2, b2, a_p, b_p,
        wg_self, wg_gath, bg, wsP, wsN, wsflag, rp, out, N);
}